// Round 9
// baseline (962.929 us; speedup 1.0000x reference)
//
#include <hip/hip_runtime.h>
#include <stdint.h>
#include <stddef.h>

typedef unsigned short bf16u;
typedef __attribute__((ext_vector_type(8))) short short8;
typedef __attribute__((ext_vector_type(4))) float f32x4;

__device__ __forceinline__ bf16u f2bf(float f) {
  union { float f; unsigned u; } v; v.f = f;
  unsigned r = v.u + 0x7FFFu + ((v.u >> 16) & 1u);
  return (bf16u)(r >> 16);
}

#define GL16(g, l) __builtin_amdgcn_global_load_lds( \
    (const __attribute__((address_space(1))) unsigned int*)(g), \
    (__attribute__((address_space(3))) unsigned int*)(l), 16, 0, 0)

// ---------------- GEMM: 128x128 tile, BK=32, dbuf global_load_lds (m97) ----
enum { EPI_BF16 = 0, EPI_RELU_GATE = 1, EPI_QKV = 2, EPI_RES = 3, EPI_F32ACC = 4, EPI_KV = 5 };

template<int EPI>
__global__ __launch_bounds__(256, 3) void gemm_k(
    const bf16u* __restrict__ A, int LDA,
    const bf16u* __restrict__ BT, int LDB,
    const float* __restrict__ bias, const float* __restrict__ res,
    const float* __restrict__ gates,
    bf16u* __restrict__ o1, bf16u* __restrict__ o2, bf16u* __restrict__ o3,
    float* __restrict__ of,
    int N, int K, int slog, int egate0, int firste)
{
  __shared__ bf16u Ab[2][128 * 32];
  __shared__ bf16u Bb[2][128 * 32];
  const int tid = threadIdx.x, lane = tid & 63, w = tid >> 6;
  const int wm = w >> 1, wn = w & 1;
  const int cpx = gridDim.x >> 3;
  const int bid = (blockIdx.x & 7) * cpx + (blockIdx.x >> 3);
  const int nbt = N >> 7;
  const int mt = bid / nbt, nt = bid - mt * nbt;
  const int bm = mt << 7, bn = nt << 7;

  const int srow = lane >> 2;
  const int scol = (lane & 3) << 3;
  const bf16u* ap0 = A + (size_t)(bm + w * 16 + srow) * LDA + scol;
  const bf16u* ap1 = ap0 + (size_t)64 * LDA;
  const bf16u* bp0 = BT + (size_t)(bn + w * 16 + srow) * LDB + scol;
  const bf16u* bp1 = bp0 + (size_t)64 * LDB;

  f32x4 acc[4][4] = {};
  const int NT = K >> 5;

  GL16(ap0, &Ab[0][w * 512]);
  GL16(ap1, &Ab[0][(4 + w) * 512]);
  GL16(bp0, &Bb[0][w * 512]);
  GL16(bp1, &Bb[0][(4 + w) * 512]);
  __syncthreads();

  const int rl = lane & 15, kg = (lane >> 4) << 3;
  int cur = 0;
  for (int kt = 0; kt < NT; ++kt) {
    if (kt + 1 < NT) {
      const int ko = (kt + 1) << 5;
      const int nb = cur ^ 1;
      GL16(ap0 + ko, &Ab[nb][w * 512]);
      GL16(ap1 + ko, &Ab[nb][(4 + w) * 512]);
      GL16(bp0 + ko, &Bb[nb][w * 512]);
      GL16(bp1 + ko, &Bb[nb][(4 + w) * 512]);
    }
    short8 af[4], bfv[4];
    #pragma unroll
    for (int i = 0; i < 4; ++i)
      af[i] = *(const short8*)&Ab[cur][(wm * 64 + i * 16 + rl) * 32 + kg];
    #pragma unroll
    for (int j = 0; j < 4; ++j)
      bfv[j] = *(const short8*)&Bb[cur][(wn * 64 + j * 16 + rl) * 32 + kg];
    #pragma unroll
    for (int i = 0; i < 4; ++i)
      #pragma unroll
      for (int j = 0; j < 4; ++j)
        acc[i][j] = __builtin_amdgcn_mfma_f32_16x16x32_bf16(af[i], bfv[j], acc[i][j], 0, 0, 0);
    __syncthreads();
    cur ^= 1;
  }

  const int r0 = bm + wm * 64, c0 = bn + wn * 64;
  const int rsub = (lane >> 4) << 2;
  #pragma unroll
  for (int j = 0; j < 4; ++j) {
    const int col = c0 + j * 16 + rl;
    const float bs = bias ? bias[col] : 0.f;
    #pragma unroll
    for (int i = 0; i < 4; ++i) {
      const f32x4 v = acc[i][j];
      #pragma unroll
      for (int jj = 0; jj < 4; ++jj) {
        const int row = r0 + i * 16 + rsub + jj;
        const float val = v[jj] + bs;
        if (EPI == EPI_BF16) {
          o1[(size_t)row * N + col] = f2bf(val);
        } else if (EPI == EPI_RELU_GATE) {
          const float g = gates[(size_t)row * 4 + egate0 + (col >> 11)];
          o1[(size_t)row * N + col] = f2bf(g * (val > 0.f ? val : 0.f));
        } else if (EPI == EPI_QKV) {
          if (col < 512) o1[(size_t)row * 512 + col] = f2bf(val);
          else if (col < 1024) o2[(size_t)row * 512 + col - 512] = f2bf(val);
          else {
            const int c = col - 1024;
            const int b_ = row >> slog, t_ = row & ((1 << slog) - 1);
            o3[(((size_t)(b_ * 8 + (c >> 6)) << 6) + (size_t)(c & 63)) * ((size_t)1 << slog) + t_] = f2bf(val);
          }
        } else if (EPI == EPI_KV) {
          if (col < 512) o2[(size_t)row * 512 + col] = f2bf(val);
          else {
            const int c = col - 512;
            const int b_ = row >> slog, t_ = row & ((1 << slog) - 1);
            o3[(((size_t)(b_ * 8 + (c >> 6)) << 6) + (size_t)(c & 63)) * ((size_t)1 << slog) + t_] = f2bf(val);
          }
        } else if (EPI == EPI_RES) {
          of[(size_t)row * N + col] = res[(size_t)row * N + col] + val;
        } else { // EPI_F32ACC
          const size_t oi = (size_t)row * N + col;
          of[oi] = firste ? val : (of[oi] + val);
        }
      }
    }
  }
}

// ---------------- Flash attention: 128 q-rows/block (2 groups/wave) --------
// LDS-staged K/V (dbuf, 1 barrier/tile); K,V fragments shared by both groups.
#define SOFTMAX_G(stv, mlv, llv, oaccv, pbX, DOMASK, QG)                      \
  {                                                                           \
    float sv[16]; float pm = -1e30f;                                          \
    _Pragma("unroll")                                                         \
    for (int mi = 0; mi < 4; ++mi) {                                          \
      _Pragma("unroll")                                                       \
      for (int jj = 0; jj < 4; ++jj) {                                        \
        float s_ = stv[mi][jj] * SC;                                          \
        if (DOMASK) {                                                         \
          const int kgi = kt * 64 + mi * 16 + g4 * 4 + jj;                    \
          if (kgi > (QG)) s_ = -1e30f;                                        \
        }                                                                     \
        sv[mi * 4 + jj] = s_; pm = fmaxf(pm, s_);                             \
      }                                                                       \
    }                                                                         \
    pm = fmaxf(pm, __shfl_xor(pm, 16));                                       \
    pm = fmaxf(pm, __shfl_xor(pm, 32));                                       \
    const float mnew = fmaxf(mlv, pm);                                        \
    const float alpha = exp2f(mlv - mnew);                                    \
    float ps = 0.f;                                                           \
    _Pragma("unroll")                                                         \
    for (int mi = 0; mi < 4; ++mi) {                                          \
      const float p0_ = exp2f(sv[mi * 4 + 0] - mnew);                         \
      const float p1_ = exp2f(sv[mi * 4 + 1] - mnew);                         \
      const float p2_ = exp2f(sv[mi * 4 + 2] - mnew);                         \
      const float p3_ = exp2f(sv[mi * 4 + 3] - mnew);                         \
      ps += (p0_ + p1_) + (p2_ + p3_);                                        \
      const unsigned w0_ = (unsigned)f2bf(p0_) | ((unsigned)f2bf(p1_) << 16); \
      const unsigned w1_ = (unsigned)f2bf(p2_) | ((unsigned)f2bf(p3_) << 16); \
      *(unsigned*)(pbX + ((mi * 32 + g4 * 8 + 0) ^ swq)) = w0_;               \
      *(unsigned*)(pbX + ((mi * 32 + g4 * 8 + 4) ^ swq)) = w1_;               \
    }                                                                         \
    ps += __shfl_xor(ps, 16);                                                 \
    ps += __shfl_xor(ps, 32);                                                 \
    llv = llv * alpha + ps; mlv = mnew;                                       \
    _Pragma("unroll")                                                         \
    for (int jj = 0; jj < 4; ++jj) {                                          \
      const float aj = __shfl(alpha, g4 * 4 + jj);                            \
      _Pragma("unroll")                                                       \
      for (int ni = 0; ni < 4; ++ni) oaccv[ni][jj] *= aj;                     \
    }                                                                         \
  }

template<bool CAUSAL>
__global__ __launch_bounds__(256, 3) void attn_k(
    const bf16u* __restrict__ Q, const bf16u* __restrict__ Kg,
    const bf16u* __restrict__ VT, bf16u* __restrict__ O,
    int Sq, int Sk)
{
  __shared__ bf16u Kl[2][64 * 64];
  __shared__ bf16u Vl[2][64 * 64];
  __shared__ bf16u Pl[128 * 64];
  const int nqt = Sq >> 7;
  const int cpx = gridDim.x >> 3;
  const int bid = (blockIdx.x & 7) * cpx + (blockIdx.x >> 3);
  const int bh = bid / nqt;
  int qt = bid - bh * nqt;
  if (CAUSAL) qt = nqt - 1 - qt;       // long blocks first
  const int b = bh >> 3, h = bh & 7;
  const int tid = threadIdx.x, lane = tid & 63, w = tid >> 6;
  const int rl = lane & 15, g4 = lane >> 4;

  const int qr = w * 16 + rl;          // 0..63 within group
  const int qbase = qt * 128;

  const bf16u* qp0 = Q + (size_t)(b * Sq + qbase + qr) * 512 + h * 64 + g4 * 8;
  const bf16u* qp1 = qp0 + (size_t)64 * 512;
  const short8 qa0 = *(const short8*)qp0;
  const short8 qa1 = *(const short8*)(qp0 + 32);
  const short8 qc0 = *(const short8*)qp1;
  const short8 qc1 = *(const short8*)(qp1 + 32);

  f32x4 oacc0[4] = {}, oacc1[4] = {};
  float ml0 = -1e30f, ll0 = 0.f, ml1 = -1e30f, ll1 = 0.f;
  const int KT = CAUSAL ? (2 * qt + 2) : (Sk >> 6);

  const int str = tid >> 2, stc = tid & 3;
  const int sw_st = (str & 7) << 4;
  const bf16u* kq = Kg + (size_t)(b * Sk + str) * 512 + h * 64 + stc * 8;
  const bf16u* vq = VT + (size_t)(bh * 64 + str) * Sk + stc * 8;
  const int lo0 = str * 128 + ((stc * 16) ^ sw_st);
  const int lo1 = str * 128 + ((stc * 16 + 64) ^ sw_st);

  char* const pb0 = (char*)Pl + qr * 128;
  char* const pb1 = (char*)Pl + (64 + qr) * 128;
  const int swq = (qr & 7) << 4;
  const float SC = 0.125f * 1.44269504f;

  {
    const short8 k0 = *(const short8*)kq;
    const short8 k1 = *(const short8*)(kq + 32);
    const short8 v0 = *(const short8*)vq;
    const short8 v1 = *(const short8*)(vq + 32);
    *(short8*)((char*)Kl[0] + lo0) = k0;
    *(short8*)((char*)Kl[0] + lo1) = k1;
    *(short8*)((char*)Vl[0] + lo0) = v0;
    *(short8*)((char*)Vl[0] + lo1) = v1;
  }
  __syncthreads();

  int cur = 0;
  for (int kt = 0; kt < KT; ++kt) {
    short8 nk0, nk1, nv0, nv1;
    const bool pre = (kt + 1 < KT);
    if (pre) {
      const bf16u* ks = kq + (size_t)(kt + 1) * 64 * 512;
      const bf16u* vs = vq + (kt + 1) * 64;
      nk0 = *(const short8*)ks;
      nk1 = *(const short8*)(ks + 32);
      nv0 = *(const short8*)vs;
      nv1 = *(const short8*)(vs + 32);
    }

    const bool mask0 = CAUSAL && (kt == 2 * qt);
    const bool skip0 = CAUSAL && (kt == 2 * qt + 1);
    const bool mask1 = CAUSAL && (kt == 2 * qt + 1);

    const bf16u* Kc = Kl[cur];
    const bf16u* Vc = Vl[cur];
    f32x4 st0[4] = {}, st1[4] = {};
    #pragma unroll
    for (int mi = 0; mi < 4; ++mi) {
      const int kr = mi * 16 + rl;
      const char* kb_ = (const char*)Kc + kr * 128;
      const int sw = (kr & 7) << 4;
      const short8 kf0 = *(const short8*)(kb_ + ((g4 * 16) ^ sw));
      const short8 kf1 = *(const short8*)(kb_ + ((g4 * 16 + 64) ^ sw));
      if (!skip0) {
        st0[mi] = __builtin_amdgcn_mfma_f32_16x16x32_bf16(kf0, qa0, st0[mi], 0, 0, 0);
        st0[mi] = __builtin_amdgcn_mfma_f32_16x16x32_bf16(kf1, qa1, st0[mi], 0, 0, 0);
      }
      st1[mi] = __builtin_amdgcn_mfma_f32_16x16x32_bf16(kf0, qc0, st1[mi], 0, 0, 0);
      st1[mi] = __builtin_amdgcn_mfma_f32_16x16x32_bf16(kf1, qc1, st1[mi], 0, 0, 0);
    }

    if (!skip0) SOFTMAX_G(st0, ml0, ll0, oacc0, pb0, mask0, qbase + qr);
    SOFTMAX_G(st1, ml1, ll1, oacc1, pb1, mask1, qbase + 64 + qr);

    asm volatile("s_waitcnt lgkmcnt(0)" ::: "memory");
    #pragma unroll
    for (int ks = 0; ks < 2; ++ks) {
      const short8 pf0 = *(const short8*)(pb0 + ((g4 * 16 + ks * 64) ^ swq));
      const short8 pf1 = *(const short8*)(pb1 + ((g4 * 16 + ks * 64) ^ swq));
      #pragma unroll
      for (int ni = 0; ni < 4; ++ni) {
        const int vr = ni * 16 + rl;
        const short8 vf = *(const short8*)((const char*)Vc + vr * 128 + ((g4 * 16 + ks * 64) ^ ((vr & 7) << 4)));
        if (!skip0) oacc0[ni] = __builtin_amdgcn_mfma_f32_16x16x32_bf16(pf0, vf, oacc0[ni], 0, 0, 0);
        oacc1[ni] = __builtin_amdgcn_mfma_f32_16x16x32_bf16(pf1, vf, oacc1[ni], 0, 0, 0);
      }
    }

    if (pre) {
      const int nb = cur ^ 1;
      *(short8*)((char*)Kl[nb] + lo0) = nk0;
      *(short8*)((char*)Kl[nb] + lo1) = nk1;
      *(short8*)((char*)Vl[nb] + lo0) = nv0;
      *(short8*)((char*)Vl[nb] + lo1) = nv1;
    }
    __syncthreads();
    cur ^= 1;
  }

  #pragma unroll
  for (int jj = 0; jj < 4; ++jj) {
    const float l0 = __shfl(ll0, g4 * 4 + jj);
    const float l1 = __shfl(ll1, g4 * 4 + jj);
    const float i0 = 1.f / l0, i1 = 1.f / l1;
    const int row = qbase + w * 16 + g4 * 4 + jj;
    #pragma unroll
    for (int ni = 0; ni < 4; ++ni) {
      O[(size_t)(b * Sq + row) * 512 + h * 64 + ni * 16 + rl] = f2bf(oacc0[ni][jj] * i0);
      O[(size_t)(b * Sq + row + 64) * 512 + h * 64 + ni * 16 + rl] = f2bf(oacc1[ni][jj] * i1);
    }
  }
}

// ---------------- LayerNorm (wave/row), optional fused gating --------------
template<bool ADD, bool BOUT, bool GATE>
__global__ __launch_bounds__(256, 4) void ln_k(
    const float* __restrict__ X, const float* __restrict__ Y,
    const float* __restrict__ gam, const float* __restrict__ bet,
    float* __restrict__ outf, bf16u* __restrict__ outb,
    const float* __restrict__ gw, const float* __restrict__ gb,
    float* __restrict__ gates, float* __restrict__ imp)
{
  __shared__ float sh[4];
  const int tid = threadIdx.x;
  if (GATE) {
    if (tid < 4) sh[tid] = 0.f;
    __syncthreads();
  }
  const int row = blockIdx.x * 4 + (tid >> 6);
  const int lane = tid & 63;
  const float* xp = X + (size_t)row * 512 + lane * 8;
  float v[8];
  {
    const float4 t0 = *(const float4*)xp;
    const float4 t1 = *(const float4*)(xp + 4);
    v[0] = t0.x; v[1] = t0.y; v[2] = t0.z; v[3] = t0.w;
    v[4] = t1.x; v[5] = t1.y; v[6] = t1.z; v[7] = t1.w;
  }
  if (ADD) {
    const float* yp = Y + (size_t)row * 512 + lane * 8;
    const float4 t0 = *(const float4*)yp;
    const float4 t1 = *(const float4*)(yp + 4);
    v[0] += t0.x; v[1] += t0.y; v[2] += t0.z; v[3] += t0.w;
    v[4] += t1.x; v[5] += t1.y; v[6] += t1.z; v[7] += t1.w;
  }
  float s = 0.f, q = 0.f;
  #pragma unroll
  for (int i = 0; i < 8; ++i) { s += v[i]; q += v[i] * v[i]; }
  #pragma unroll
  for (int off = 1; off < 64; off <<= 1) {
    s += __shfl_xor(s, off);
    q += __shfl_xor(q, off);
  }
  const float mean = s * (1.f / 512.f);
  const float var = q * (1.f / 512.f) - mean * mean;
  const float rs = rsqrtf(var + 1e-5f);
  float o[8];
  #pragma unroll
  for (int i = 0; i < 8; ++i)
    o[i] = (v[i] - mean) * rs * gam[lane * 8 + i] + bet[lane * 8 + i];
  float* op = outf + (size_t)row * 512 + lane * 8;
  *(float4*)op = make_float4(o[0], o[1], o[2], o[3]);
  *(float4*)(op + 4) = make_float4(o[4], o[5], o[6], o[7]);
  if (BOUT) {
    union { bf16u u[8]; short8 v8; } pk;
    #pragma unroll
    for (int i = 0; i < 8; ++i) pk.u[i] = f2bf(o[i]);
    *(short8*)(outb + (size_t)row * 512 + lane * 8) = pk.v8;
  }
  if (GATE) {
    float a0 = 0.f, a1 = 0.f, a2 = 0.f, a3 = 0.f;
    #pragma unroll
    for (int i = 0; i < 8; ++i) {
      const float4 wv = *(const float4*)(gw + (lane * 8 + i) * 4);
      a0 += o[i] * wv.x; a1 += o[i] * wv.y; a2 += o[i] * wv.z; a3 += o[i] * wv.w;
    }
    #pragma unroll
    for (int off = 1; off < 64; off <<= 1) {
      a0 += __shfl_xor(a0, off); a1 += __shfl_xor(a1, off);
      a2 += __shfl_xor(a2, off); a3 += __shfl_xor(a3, off);
    }
    if (lane == 0) {
      a0 += gb[0]; a1 += gb[1]; a2 += gb[2]; a3 += gb[3];
      const float m = fmaxf(fmaxf(a0, a1), fmaxf(a2, a3));
      const float e0 = exp2f((a0 - m) * 1.44269504f);
      const float e1 = exp2f((a1 - m) * 1.44269504f);
      const float e2 = exp2f((a2 - m) * 1.44269504f);
      const float e3 = exp2f((a3 - m) * 1.44269504f);
      const float inv = 1.f / (e0 + e1 + e2 + e3);
      float* gr = gates + (size_t)row * 4;
      const float g0 = e0 * inv, g1 = e1 * inv, g2 = e2 * inv, g3 = e3 * inv;
      gr[0] = g0; gr[1] = g1; gr[2] = g2; gr[3] = g3;
      atomicAdd(&sh[0], g0); atomicAdd(&sh[1], g1);
      atomicAdd(&sh[2], g2); atomicAdd(&sh[3], g3);
    }
    __syncthreads();
    if (tid < 4) atomicAdd(&imp[tid], sh[tid]);
  }
}

// final LN: out = LN(x + y + sum_e g_e*b2_e)
__global__ __launch_bounds__(256, 4) void ln_final_k(
    const float* __restrict__ X, const float* __restrict__ Y,
    const float* __restrict__ gates, const float* __restrict__ b2,
    const float* __restrict__ gam, const float* __restrict__ bet,
    float* __restrict__ outf)
{
  const int row = blockIdx.x * 4 + (threadIdx.x >> 6);
  const int lane = threadIdx.x & 63;
  const float4 gv4 = *(const float4*)(gates + (size_t)row * 4);
  float v[8];
  {
    const float* xp = X + (size_t)row * 512 + lane * 8;
    const float* yp = Y + (size_t)row * 512 + lane * 8;
    const float4 t0 = *(const float4*)xp;
    const float4 t1 = *(const float4*)(xp + 4);
    const float4 u0 = *(const float4*)yp;
    const float4 u1 = *(const float4*)(yp + 4);
    v[0] = t0.x + u0.x; v[1] = t0.y + u0.y; v[2] = t0.z + u0.z; v[3] = t0.w + u0.w;
    v[4] = t1.x + u1.x; v[5] = t1.y + u1.y; v[6] = t1.z + u1.z; v[7] = t1.w + u1.w;
  }
  #pragma unroll
  for (int e = 0; e < 4; ++e) {
    const float ge = e == 0 ? gv4.x : e == 1 ? gv4.y : e == 2 ? gv4.z : gv4.w;
    const float4 b0 = *(const float4*)(b2 + e * 512 + lane * 8);
    const float4 b1 = *(const float4*)(b2 + e * 512 + lane * 8 + 4);
    v[0] += ge * b0.x; v[1] += ge * b0.y; v[2] += ge * b0.z; v[3] += ge * b0.w;
    v[4] += ge * b1.x; v[5] += ge * b1.y; v[6] += ge * b1.z; v[7] += ge * b1.w;
  }
  float s = 0.f, q = 0.f;
  #pragma unroll
  for (int i = 0; i < 8; ++i) { s += v[i]; q += v[i] * v[i]; }
  #pragma unroll
  for (int off = 1; off < 64; off <<= 1) {
    s += __shfl_xor(s, off);
    q += __shfl_xor(q, off);
  }
  const float mean = s * (1.f / 512.f);
  const float var = q * (1.f / 512.f) - mean * mean;
  const float rs = rsqrtf(var + 1e-5f);
  float* op = outf + (size_t)row * 512 + lane * 8;
  float o[8];
  #pragma unroll
  for (int i = 0; i < 8; ++i)
    o[i] = (v[i] - mean) * rs * gam[lane * 8 + i] + bet[lane * 8 + i];
  *(float4*)op = make_float4(o[0], o[1], o[2], o[3]);
  *(float4*)(op + 4) = make_float4(o[4], o[5], o[6], o[7]);
}

__global__ void aux_k(const float* __restrict__ imp, float* __restrict__ out) {
  if (threadIdx.x == 0 && blockIdx.x == 0) {
    float s = 0.f;
    #pragma unroll
    for (int e = 0; e < 4; ++e) { const float v = imp[e] * (1.f / 16384.f); s += v * v; }
    out[0] = 4.f * s;
  }
}

// ---------------- convert / batched transposes -----------------------------
__global__ __launch_bounds__(256, 4) void conv_k(const float* __restrict__ in, bf16u* __restrict__ out) {
  const size_t i = ((size_t)blockIdx.x * 256 + threadIdx.x) * 8;
  const float4 a = *(const float4*)(in + i);
  const float4 b = *(const float4*)(in + i + 4);
  union { bf16u u[8]; short8 v; } pk;
  pk.u[0] = f2bf(a.x); pk.u[1] = f2bf(a.y); pk.u[2] = f2bf(a.z); pk.u[3] = f2bf(a.w);
  pk.u[4] = f2bf(b.x); pk.u[5] = f2bf(b.y); pk.u[6] = f2bf(b.z); pk.u[7] = f2bf(b.w);
  *(short8*)(out + i) = pk.v;
}

struct P8 { const float* w[8]; };

__global__ __launch_bounds__(256, 4) void trans8_k(
    P8 ps, bf16u* __restrict__ WT0, int K, int N)
{
  const float* W = ps.w[blockIdx.z];
  bf16u* WT = WT0 + (size_t)blockIdx.z * K * N;
  __shared__ float t[32][33];
  const int tx = threadIdx.x & 31, ty = threadIdx.x >> 5;
  const int n0 = blockIdx.x * 32, k0 = blockIdx.y * 32;
  #pragma unroll
  for (int i = 0; i < 4; ++i)
    t[ty + i * 8][tx] = W[(size_t)(k0 + ty + i * 8) * N + n0 + tx];
  __syncthreads();
  #pragma unroll
  for (int i = 0; i < 4; ++i)
    WT[(size_t)(n0 + ty + i * 8) * K + k0 + tx] = f2bf(t[tx][ty + i * 8]);
}

__global__ __launch_bounds__(256, 4) void trans_s_k(
    const float* __restrict__ W0, size_t wstride,
    bf16u* __restrict__ WT0, size_t tstride, int K, int N)
{
  const float* W = W0 + (size_t)blockIdx.z * wstride;
  bf16u* WT = WT0 + (size_t)blockIdx.z * tstride;
  __shared__ float t[32][33];
  const int tx = threadIdx.x & 31, ty = threadIdx.x >> 5;
  const int n0 = blockIdx.x * 32, k0 = blockIdx.y * 32;
  #pragma unroll
  for (int i = 0; i < 4; ++i)
    t[ty + i * 8][tx] = W[(size_t)(k0 + ty + i * 8) * N + n0 + tx];
  __syncthreads();
  #pragma unroll
  for (int i = 0; i < 4; ++i)
    WT[(size_t)(n0 + ty + i * 8) * K + k0 + tx] = f2bf(t[tx][ty + i * 8]);
}

// ---------------- host orchestration -------------------------------------
extern "C" void kernel_launch(void* const* d_in, const int* in_sizes, int n_in,
                              void* d_out, int out_size, void* d_ws, size_t ws_size,
                              hipStream_t stream)
{
  const int B = 16, S = 1024, T = 512, D = 512, DF = 2048, E = 4;
  const int M = B * S;      // 16384
  const int Mc = B * T;     // 8192
  (void)in_sizes; (void)n_in; (void)out_size;

  const float* x      = (const float*)d_in[0];
  const float* cross  = (const float*)d_in[1];
  const float* gate_w = (const float*)d_in[18];
  const float* gate_b = (const float*)d_in[19];
  const float* exp_w1 = (const float*)d_in[20];
  const float* exp_b1 = (const float*)d_in[21];
  const float* exp_w2 = (const float*)d_in[22];
  const float* exp_b2 = (const float*)d_in[23];

  char* p = (char*)d_ws;
  auto alloc = [&](size_t bytes) -> char* {
    char* r = p;
    p += (bytes + 255) & ~(size_t)255;
    return r;
  };
  // ---- persistent ----
  bf16u* w1T   = (bf16u*)alloc((size_t)E * DF * D * 2);   // [8192][512]
  bf16u* w2T   = (bf16u*)alloc((size_t)D * E * DF * 2);   // [512][8192]
  float* xf    = (float*)alloc((size_t)M * D * 4);
  bf16u* x2b   = (bf16u*)alloc((size_t)M * D * 2);
  float* gates = (float*)alloc((size_t)M * 4 * 4);
  float* imp   = (float*)alloc(256);
  float* y     = (float*)alloc((size_t)M * D * 4);
  float* qkvb  = (float*)alloc(1536 * 4);
  float* kvb   = (float*)alloc(1024 * 4);

  // ---- union region: attn-phase scratch OR MoE hbuf ----
  char* upool = p;
  bf16u* xb  = (bf16u*)upool;
  bf16u* crb = xb  + (size_t)M * D;
  bf16u* wT  = crb + (size_t)Mc * D;
  bf16u* qb  = wT  + (size_t)8 * D * D;
  bf16u* kb  = qb  + (size_t)M * D;
  bf16u* vTb = kb  + (size_t)M * D;
  bf16u* ao  = vTb + (size_t)M * D;
  const size_t attnPool = ((size_t)M * D * 5 + (size_t)Mc * D + (size_t)8 * D * D) * 2;
  bf16u* hbuf = (bf16u*)upool;
  const size_t persistent = (size_t)(upool - (char*)d_ws);
  const size_t perE = (size_t)M * DF * 2;   // 67.1 MB
  const size_t rem = ws_size > persistent ? ws_size - persistent : 0;
  const int EC = (rem >= 4 * perE && rem >= attnPool) ? 4
               : (rem >= 2 * perE && rem >= attnPool) ? 2 : 1;

  hipMemsetAsync(imp, 0, 32, stream);
  hipMemcpyAsync(qkvb,        d_in[3], 512 * 4, hipMemcpyDeviceToDevice, stream);
  hipMemcpyAsync(qkvb + 512,  d_in[5], 512 * 4, hipMemcpyDeviceToDevice, stream);
  hipMemcpyAsync(qkvb + 1024, d_in[7], 512 * 4, hipMemcpyDeviceToDevice, stream);
  hipMemcpyAsync(kvb,         d_in[13], 512 * 4, hipMemcpyDeviceToDevice, stream);
  hipMemcpyAsync(kvb + 512,   d_in[15], 512 * 4, hipMemcpyDeviceToDevice, stream);

  conv_k<<<(M * D) / 2048, 256, 0, stream>>>(x, xb);
  conv_k<<<(Mc * D) / 2048, 256, 0, stream>>>(cross, crb);
  {
    P8 ps;
    for (int i = 0; i < 8; ++i) ps.w[i] = (const float*)d_in[2 + 2 * i];
    trans8_k<<<dim3(D / 32, D / 32, 8), 256, 0, stream>>>(ps, wT, D, D);
  }
  trans_s_k<<<dim3(DF / 32, D / 32, 4), 256, 0, stream>>>(
      exp_w1, (size_t)D * DF, w1T, (size_t)DF * D, D, DF);
  trans_s_k<<<dim3(D / 32, (E * DF) / 32, 1), 256, 0, stream>>>(
      exp_w2, 0, w2T, 0, E * DF, D);

  const int gATT = B * 8 * (S / 128);   // 1024

  // ---- self-attention ----
  gemm_k<EPI_QKV><<<(M / 128) * 12, 256, 0, stream>>>(
      xb, 512, wT, 512, qkvb, nullptr, nullptr, qb, kb, vTb, nullptr, 1536, 512, 10, 0, 0);
  attn_k<true><<<gATT, 256, 0, stream>>>(qb, kb, vTb, ao, S, S);
  gemm_k<EPI_RES><<<(M / 128) * 4, 256, 0, stream>>>(
      ao, 512, wT + 3 * (size_t)D * D, 512, (const float*)d_in[9], x, nullptr,
      nullptr, nullptr, nullptr, xf, 512, 512, 0, 0, 0);
  ln_k<false, true, false><<<M / 4, 256, 0, stream>>>(
      xf, nullptr, (const float*)d_in[24], (const float*)d_in[25], xf, x2b,
      nullptr, nullptr, nullptr, nullptr);

  // ---- cross-attention ----
  gemm_k<EPI_BF16><<<(M / 128) * 4, 256, 0, stream>>>(
      x2b, 512, wT + 4 * (size_t)D * D, 512, (const float*)d_in[11], nullptr, nullptr,
      qb, nullptr, nullptr, nullptr, 512, 512, 0, 0, 0);
  gemm_k<EPI_KV><<<(Mc / 128) * 8, 256, 0, stream>>>(
      crb, 512, wT + 5 * (size_t)D * D, 512, kvb, nullptr, nullptr,
      nullptr, kb, vTb, nullptr, 1024, 512, 9, 0, 0);
  attn_k<false><<<gATT, 256, 0, stream>>>(qb, kb, vTb, ao, S, T);
  gemm_k<EPI_RES><<<(M / 128) * 4, 256, 0, stream>>>(
      ao, 512, wT + 7 * (size_t)D * D, 512, (const float*)d_in[17], xf, nullptr,
      nullptr, nullptr, nullptr, xf, 512, 512, 0, 0, 0);
  // ln2 with fused gating (+imp accumulation)
  ln_k<false, true, true><<<M / 4, 256, 0, stream>>>(
      xf, nullptr, (const float*)d_in[26], (const float*)d_in[27], xf, x2b,
      gate_w, gate_b, gates, imp);

  // ---- MoE ----
  aux_k<<<1, 64, 0, stream>>>(imp, (float*)d_out + (size_t)M * D);
  const int NC = E / EC;
  const int Nh = EC * DF;
  for (int c = 0; c < NC; ++c) {
    gemm_k<EPI_RELU_GATE><<<(M / 128) * (Nh / 128), 256, 0, stream>>>(
        x2b, 512, w1T + (size_t)c * Nh * D, 512, exp_b1 + (size_t)c * Nh, nullptr, gates,
        hbuf, nullptr, nullptr, nullptr, Nh, 512, 0, c * EC, 0);
    gemm_k<EPI_F32ACC><<<(M / 128) * 4, 256, 0, stream>>>(
        hbuf, Nh, w2T + (size_t)c * Nh, E * DF, nullptr, nullptr, nullptr,
        nullptr, nullptr, nullptr, y, 512, Nh, 0, 0, c == 0 ? 1 : 0);
  }
  ln_final_k<<<M / 4, 256, 0, stream>>>(xf, y, gates, exp_b2, (const float*)d_in[28], (const float*)d_in[29], (float*)d_out);
}

// Round 10
// 869.417 us; speedup vs baseline: 1.1076x; 1.1076x over previous
//
#include <hip/hip_runtime.h>
#include <stdint.h>
#include <stddef.h>

typedef unsigned short bf16u;
typedef __attribute__((ext_vector_type(8))) short short8;
typedef __attribute__((ext_vector_type(4))) float f32x4;

__device__ __forceinline__ bf16u f2bf(float f) {
  union { float f; unsigned u; } v; v.f = f;
  unsigned r = v.u + 0x7FFFu + ((v.u >> 16) & 1u);
  return (bf16u)(r >> 16);
}

#define GL16(g, l) __builtin_amdgcn_global_load_lds( \
    (const __attribute__((address_space(1))) unsigned int*)(g), \
    (__attribute__((address_space(3))) unsigned int*)(l), 16, 0, 0)

// ---------------- GEMM: 128x128 tile, BK=32, dbuf global_load_lds (m97) ----
enum { EPI_BF16 = 0, EPI_RELU_GATE = 1, EPI_QKV = 2, EPI_RES = 3, EPI_F32ACC = 4, EPI_KV = 5 };

template<int EPI>
__global__ __launch_bounds__(256, 3) void gemm_k(
    const bf16u* __restrict__ A, int LDA,
    const bf16u* __restrict__ BT, int LDB,
    const float* __restrict__ bias, const float* __restrict__ res,
    const float* __restrict__ gates,
    bf16u* __restrict__ o1, bf16u* __restrict__ o2, bf16u* __restrict__ o3,
    float* __restrict__ of,
    int N, int K, int slog, int egate0, int firste)
{
  __shared__ bf16u Ab[2][128 * 32];
  __shared__ bf16u Bb[2][128 * 32];
  const int tid = threadIdx.x, lane = tid & 63, w = tid >> 6;
  const int wm = w >> 1, wn = w & 1;
  const int cpx = gridDim.x >> 3;
  const int bid = (blockIdx.x & 7) * cpx + (blockIdx.x >> 3);
  const int nbt = N >> 7;
  const int mt = bid / nbt, nt = bid - mt * nbt;
  const int bm = mt << 7, bn = nt << 7;

  const int srow = lane >> 2;
  const int scol = (lane & 3) << 3;
  const bf16u* ap0 = A + (size_t)(bm + w * 16 + srow) * LDA + scol;
  const bf16u* ap1 = ap0 + (size_t)64 * LDA;
  const bf16u* bp0 = BT + (size_t)(bn + w * 16 + srow) * LDB + scol;
  const bf16u* bp1 = bp0 + (size_t)64 * LDB;

  f32x4 acc[4][4] = {};
  const int NT = K >> 5;

  GL16(ap0, &Ab[0][w * 512]);
  GL16(ap1, &Ab[0][(4 + w) * 512]);
  GL16(bp0, &Bb[0][w * 512]);
  GL16(bp1, &Bb[0][(4 + w) * 512]);
  __syncthreads();

  const int rl = lane & 15, kg = (lane >> 4) << 3;
  int cur = 0;
  for (int kt = 0; kt < NT; ++kt) {
    if (kt + 1 < NT) {
      const int ko = (kt + 1) << 5;
      const int nb = cur ^ 1;
      GL16(ap0 + ko, &Ab[nb][w * 512]);
      GL16(ap1 + ko, &Ab[nb][(4 + w) * 512]);
      GL16(bp0 + ko, &Bb[nb][w * 512]);
      GL16(bp1 + ko, &Bb[nb][(4 + w) * 512]);
    }
    short8 af[4], bfv[4];
    #pragma unroll
    for (int i = 0; i < 4; ++i)
      af[i] = *(const short8*)&Ab[cur][(wm * 64 + i * 16 + rl) * 32 + kg];
    #pragma unroll
    for (int j = 0; j < 4; ++j)
      bfv[j] = *(const short8*)&Bb[cur][(wn * 64 + j * 16 + rl) * 32 + kg];
    #pragma unroll
    for (int i = 0; i < 4; ++i)
      #pragma unroll
      for (int j = 0; j < 4; ++j)
        acc[i][j] = __builtin_amdgcn_mfma_f32_16x16x32_bf16(af[i], bfv[j], acc[i][j], 0, 0, 0);
    __syncthreads();
    cur ^= 1;
  }

  const int r0 = bm + wm * 64, c0 = bn + wn * 64;
  const int rsub = (lane >> 4) << 2;
  #pragma unroll
  for (int j = 0; j < 4; ++j) {
    const int col = c0 + j * 16 + rl;
    const float bs = bias ? bias[col] : 0.f;
    #pragma unroll
    for (int i = 0; i < 4; ++i) {
      const f32x4 v = acc[i][j];
      #pragma unroll
      for (int jj = 0; jj < 4; ++jj) {
        const int row = r0 + i * 16 + rsub + jj;
        const float val = v[jj] + bs;
        if (EPI == EPI_BF16) {
          o1[(size_t)row * N + col] = f2bf(val);
        } else if (EPI == EPI_RELU_GATE) {
          const float g = gates[(size_t)row * 4 + egate0 + (col >> 11)];
          o1[(size_t)row * N + col] = f2bf(g * (val > 0.f ? val : 0.f));
        } else if (EPI == EPI_QKV) {
          if (col < 512) o1[(size_t)row * 512 + col] = f2bf(val);
          else if (col < 1024) o2[(size_t)row * 512 + col - 512] = f2bf(val);
          else {
            const int c = col - 1024;
            const int b_ = row >> slog, t_ = row & ((1 << slog) - 1);
            o3[(((size_t)(b_ * 8 + (c >> 6)) << 6) + (size_t)(c & 63)) * ((size_t)1 << slog) + t_] = f2bf(val);
          }
        } else if (EPI == EPI_KV) {
          if (col < 512) o2[(size_t)row * 512 + col] = f2bf(val);
          else {
            const int c = col - 512;
            const int b_ = row >> slog, t_ = row & ((1 << slog) - 1);
            o3[(((size_t)(b_ * 8 + (c >> 6)) << 6) + (size_t)(c & 63)) * ((size_t)1 << slog) + t_] = f2bf(val);
          }
        } else if (EPI == EPI_RES) {
          of[(size_t)row * N + col] = res[(size_t)row * N + col] + val;
        } else { // EPI_F32ACC
          const size_t oi = (size_t)row * N + col;
          of[oi] = firste ? val : (of[oi] + val);
        }
      }
    }
  }
}

// ---------------- Flash attention (round-8 structure: best measured) -------
template<bool CAUSAL>
__global__ __launch_bounds__(256, 4) void attn_k(
    const bf16u* __restrict__ Q, const bf16u* __restrict__ Kg,
    const bf16u* __restrict__ VT, bf16u* __restrict__ O,
    int Sq, int Sk)
{
  __shared__ bf16u Kl[2][64 * 64];
  __shared__ bf16u Vl[2][64 * 64];
  __shared__ bf16u Pl[64 * 64];
  const int nqt = Sq >> 6;
  const int cpx = gridDim.x >> 3;
  const int bid = (blockIdx.x & 7) * cpx + (blockIdx.x >> 3);
  const int bh = bid / nqt;
  int qt = bid - bh * nqt;
  if (CAUSAL) qt = nqt - 1 - qt;     // long blocks dispatch first
  const int b = bh >> 3, h = bh & 7;
  const int tid = threadIdx.x, lane = tid & 63, w = tid >> 6;
  const int rl = lane & 15, g4 = lane >> 4;

  const int qrow = qt * 64 + w * 16 + rl;
  const bf16u* qp = Q + (size_t)(b * Sq + qrow) * 512 + h * 64 + g4 * 8;
  const short8 qf0 = *(const short8*)qp;
  const short8 qf1 = *(const short8*)(qp + 32);

  f32x4 oacc[4] = {};
  float ml = -1e30f, ll = 0.f;
  const int KT = CAUSAL ? (qt + 1) : (Sk >> 6);

  const int str = tid >> 2, stc = tid & 3;
  const int sw_st = (str & 7) << 4;
  const bf16u* kq = Kg + (size_t)(b * Sk + str) * 512 + h * 64 + stc * 8;
  const bf16u* vq = VT + (size_t)(bh * 64 + str) * Sk + stc * 8;
  const int lo0 = str * 128 + ((stc * 16) ^ sw_st);
  const int lo1 = str * 128 + ((stc * 16 + 64) ^ sw_st);

  const int qr = w * 16 + rl;
  char* const pbase = (char*)Pl + qr * 128;
  const int swq = (qr & 7) << 4;

  {
    const short8 k0 = *(const short8*)kq;
    const short8 k1 = *(const short8*)(kq + 32);
    const short8 v0 = *(const short8*)vq;
    const short8 v1 = *(const short8*)(vq + 32);
    *(short8*)((char*)Kl[0] + lo0) = k0;
    *(short8*)((char*)Kl[0] + lo1) = k1;
    *(short8*)((char*)Vl[0] + lo0) = v0;
    *(short8*)((char*)Vl[0] + lo1) = v1;
  }
  __syncthreads();

  int cur = 0;
  for (int kt = 0; kt < KT; ++kt) {
    short8 nk0, nk1, nv0, nv1;
    const bool pre = (kt + 1 < KT);
    if (pre) {
      const bf16u* ks = kq + (size_t)(kt + 1) * 64 * 512;
      const bf16u* vs = vq + (kt + 1) * 64;
      nk0 = *(const short8*)ks;
      nk1 = *(const short8*)(ks + 32);
      nv0 = *(const short8*)vs;
      nv1 = *(const short8*)(vs + 32);
    }

    const bf16u* Kc = Kl[cur];
    const bf16u* Vc = Vl[cur];
    f32x4 st[4] = {};
    #pragma unroll
    for (int mi = 0; mi < 4; ++mi) {
      const int kr = mi * 16 + rl;
      const char* kb_ = (const char*)Kc + kr * 128;
      const int sw = (kr & 7) << 4;
      const short8 kf0 = *(const short8*)(kb_ + ((g4 * 16) ^ sw));
      const short8 kf1 = *(const short8*)(kb_ + ((g4 * 16 + 64) ^ sw));
      st[mi] = __builtin_amdgcn_mfma_f32_16x16x32_bf16(kf0, qf0, st[mi], 0, 0, 0);
      st[mi] = __builtin_amdgcn_mfma_f32_16x16x32_bf16(kf1, qf1, st[mi], 0, 0, 0);
    }

    const float SC = 0.125f * 1.44269504f;
    float sv[16];
    float pm = -1e30f;
    if (CAUSAL && kt == qt) {
      const int qg = qt * 64 + qr;
      #pragma unroll
      for (int mi = 0; mi < 4; ++mi)
        #pragma unroll
        for (int jj = 0; jj < 4; ++jj) {
          float s = st[mi][jj] * SC;
          const int kgi = kt * 64 + mi * 16 + g4 * 4 + jj;
          if (kgi > qg) s = -1e30f;
          sv[mi * 4 + jj] = s;
          pm = fmaxf(pm, s);
        }
    } else {
      #pragma unroll
      for (int mi = 0; mi < 4; ++mi)
        #pragma unroll
        for (int jj = 0; jj < 4; ++jj) {
          const float s = st[mi][jj] * SC;
          sv[mi * 4 + jj] = s;
          pm = fmaxf(pm, s);
        }
    }
    pm = fmaxf(pm, __shfl_xor(pm, 16));
    pm = fmaxf(pm, __shfl_xor(pm, 32));
    const float mnew = fmaxf(ml, pm);
    const float alpha = exp2f(ml - mnew);
    float ps = 0.f;
    bf16u pb[16];
    #pragma unroll
    for (int ii = 0; ii < 16; ++ii) {
      const float p = exp2f(sv[ii] - mnew);
      ps += p;
      pb[ii] = f2bf(p);
    }
    ps += __shfl_xor(ps, 16);
    ps += __shfl_xor(ps, 32);
    ll = ll * alpha + ps;
    ml = mnew;

    #pragma unroll
    for (int jj = 0; jj < 4; ++jj) {
      const float aj = __shfl(alpha, g4 * 4 + jj);
      #pragma unroll
      for (int ni = 0; ni < 4; ++ni) oacc[ni][jj] *= aj;
    }

    #pragma unroll
    for (int mi = 0; mi < 4; ++mi) {
      #pragma unroll
      for (int jp = 0; jp < 2; ++jp) {
        const unsigned pk = (unsigned)pb[mi * 4 + jp * 2] | ((unsigned)pb[mi * 4 + jp * 2 + 1] << 16);
        const int kx2 = mi * 32 + g4 * 8 + jp * 4;
        *(unsigned*)(pbase + (kx2 ^ swq)) = pk;
      }
    }
    asm volatile("s_waitcnt lgkmcnt(0)" ::: "memory");
    #pragma unroll
    for (int ks = 0; ks < 2; ++ks) {
      const short8 pf = *(const short8*)(pbase + ((g4 * 16 + ks * 64) ^ swq));
      #pragma unroll
      for (int ni = 0; ni < 4; ++ni) {
        const int vr = ni * 16 + rl;
        const short8 vf = *(const short8*)((const char*)Vc + vr * 128 + ((g4 * 16 + ks * 64) ^ ((vr & 7) << 4)));
        oacc[ni] = __builtin_amdgcn_mfma_f32_16x16x32_bf16(pf, vf, oacc[ni], 0, 0, 0);
      }
    }

    // stage next tile into the OTHER buffer, then ONE barrier (transitive
    // ordering covers both write->read and read->overwrite hazards).
    if (pre) {
      const int nb = cur ^ 1;
      *(short8*)((char*)Kl[nb] + lo0) = nk0;
      *(short8*)((char*)Kl[nb] + lo1) = nk1;
      *(short8*)((char*)Vl[nb] + lo0) = nv0;
      *(short8*)((char*)Vl[nb] + lo1) = nv1;
    }
    __syncthreads();
    cur ^= 1;
  }

  #pragma unroll
  for (int jj = 0; jj < 4; ++jj) {
    const float lj = __shfl(ll, g4 * 4 + jj);
    const float inv = 1.f / lj;
    const int row = qt * 64 + w * 16 + g4 * 4 + jj;
    #pragma unroll
    for (int ni = 0; ni < 4; ++ni)
      O[(size_t)(b * Sq + row) * 512 + h * 64 + ni * 16 + rl] = f2bf(oacc[ni][jj] * inv);
  }
}

// ---------------- LayerNorm (wave/row), optional fused gating --------------
template<bool ADD, bool BOUT, bool GATE>
__global__ __launch_bounds__(256, 4) void ln_k(
    const float* __restrict__ X, const float* __restrict__ Y,
    const float* __restrict__ gam, const float* __restrict__ bet,
    float* __restrict__ outf, bf16u* __restrict__ outb,
    const float* __restrict__ gw, const float* __restrict__ gb,
    float* __restrict__ gates, float* __restrict__ imp)
{
  __shared__ float sh[4];
  const int tid = threadIdx.x;
  if (GATE) {
    if (tid < 4) sh[tid] = 0.f;
    __syncthreads();
  }
  const int row = blockIdx.x * 4 + (tid >> 6);
  const int lane = tid & 63;
  const float* xp = X + (size_t)row * 512 + lane * 8;
  float v[8];
  {
    const float4 t0 = *(const float4*)xp;
    const float4 t1 = *(const float4*)(xp + 4);
    v[0] = t0.x; v[1] = t0.y; v[2] = t0.z; v[3] = t0.w;
    v[4] = t1.x; v[5] = t1.y; v[6] = t1.z; v[7] = t1.w;
  }
  if (ADD) {
    const float* yp = Y + (size_t)row * 512 + lane * 8;
    const float4 t0 = *(const float4*)yp;
    const float4 t1 = *(const float4*)(yp + 4);
    v[0] += t0.x; v[1] += t0.y; v[2] += t0.z; v[3] += t0.w;
    v[4] += t1.x; v[5] += t1.y; v[6] += t1.z; v[7] += t1.w;
  }
  float s = 0.f, q = 0.f;
  #pragma unroll
  for (int i = 0; i < 8; ++i) { s += v[i]; q += v[i] * v[i]; }
  #pragma unroll
  for (int off = 1; off < 64; off <<= 1) {
    s += __shfl_xor(s, off);
    q += __shfl_xor(q, off);
  }
  const float mean = s * (1.f / 512.f);
  const float var = q * (1.f / 512.f) - mean * mean;
  const float rs = rsqrtf(var + 1e-5f);
  float o[8];
  #pragma unroll
  for (int i = 0; i < 8; ++i)
    o[i] = (v[i] - mean) * rs * gam[lane * 8 + i] + bet[lane * 8 + i];
  float* op = outf + (size_t)row * 512 + lane * 8;
  *(float4*)op = make_float4(o[0], o[1], o[2], o[3]);
  *(float4*)(op + 4) = make_float4(o[4], o[5], o[6], o[7]);
  if (BOUT) {
    union { bf16u u[8]; short8 v8; } pk;
    #pragma unroll
    for (int i = 0; i < 8; ++i) pk.u[i] = f2bf(o[i]);
    *(short8*)(outb + (size_t)row * 512 + lane * 8) = pk.v8;
  }
  if (GATE) {
    float a0 = 0.f, a1 = 0.f, a2 = 0.f, a3 = 0.f;
    #pragma unroll
    for (int i = 0; i < 8; ++i) {
      const float4 wv = *(const float4*)(gw + (lane * 8 + i) * 4);
      a0 += o[i] * wv.x; a1 += o[i] * wv.y; a2 += o[i] * wv.z; a3 += o[i] * wv.w;
    }
    #pragma unroll
    for (int off = 1; off < 64; off <<= 1) {
      a0 += __shfl_xor(a0, off); a1 += __shfl_xor(a1, off);
      a2 += __shfl_xor(a2, off); a3 += __shfl_xor(a3, off);
    }
    if (lane == 0) {
      a0 += gb[0]; a1 += gb[1]; a2 += gb[2]; a3 += gb[3];
      const float m = fmaxf(fmaxf(a0, a1), fmaxf(a2, a3));
      const float e0 = exp2f((a0 - m) * 1.44269504f);
      const float e1 = exp2f((a1 - m) * 1.44269504f);
      const float e2 = exp2f((a2 - m) * 1.44269504f);
      const float e3 = exp2f((a3 - m) * 1.44269504f);
      const float inv = 1.f / (e0 + e1 + e2 + e3);
      float* gr = gates + (size_t)row * 4;
      const float g0 = e0 * inv, g1 = e1 * inv, g2 = e2 * inv, g3 = e3 * inv;
      gr[0] = g0; gr[1] = g1; gr[2] = g2; gr[3] = g3;
      atomicAdd(&sh[0], g0); atomicAdd(&sh[1], g1);
      atomicAdd(&sh[2], g2); atomicAdd(&sh[3], g3);
    }
    __syncthreads();
    if (tid < 4) atomicAdd(&imp[tid], sh[tid]);
  }
}

// final LN: out = LN(x + y + sum_e g_e*b2_e); block 0 also emits aux loss
__global__ __launch_bounds__(256, 4) void ln_final_k(
    const float* __restrict__ X, const float* __restrict__ Y,
    const float* __restrict__ gates, const float* __restrict__ b2,
    const float* __restrict__ gam, const float* __restrict__ bet,
    float* __restrict__ outf, const float* __restrict__ imp,
    float* __restrict__ auxout)
{
  if (blockIdx.x == 0 && threadIdx.x == 0) {
    float s = 0.f;
    #pragma unroll
    for (int e = 0; e < 4; ++e) { const float v = imp[e] * (1.f / 16384.f); s += v * v; }
    auxout[0] = 4.f * s;
  }
  const int row = blockIdx.x * 4 + (threadIdx.x >> 6);
  const int lane = threadIdx.x & 63;
  const float4 gv4 = *(const float4*)(gates + (size_t)row * 4);
  float v[8];
  {
    const float* xp = X + (size_t)row * 512 + lane * 8;
    const float* yp = Y + (size_t)row * 512 + lane * 8;
    const float4 t0 = *(const float4*)xp;
    const float4 t1 = *(const float4*)(xp + 4);
    const float4 u0 = *(const float4*)yp;
    const float4 u1 = *(const float4*)(yp + 4);
    v[0] = t0.x + u0.x; v[1] = t0.y + u0.y; v[2] = t0.z + u0.z; v[3] = t0.w + u0.w;
    v[4] = t1.x + u1.x; v[5] = t1.y + u1.y; v[6] = t1.z + u1.z; v[7] = t1.w + u1.w;
  }
  #pragma unroll
  for (int e = 0; e < 4; ++e) {
    const float ge = e == 0 ? gv4.x : e == 1 ? gv4.y : e == 2 ? gv4.z : gv4.w;
    const float4 b0 = *(const float4*)(b2 + e * 512 + lane * 8);
    const float4 b1 = *(const float4*)(b2 + e * 512 + lane * 8 + 4);
    v[0] += ge * b0.x; v[1] += ge * b0.y; v[2] += ge * b0.z; v[3] += ge * b0.w;
    v[4] += ge * b1.x; v[5] += ge * b1.y; v[6] += ge * b1.z; v[7] += ge * b1.w;
  }
  float s = 0.f, q = 0.f;
  #pragma unroll
  for (int i = 0; i < 8; ++i) { s += v[i]; q += v[i] * v[i]; }
  #pragma unroll
  for (int off = 1; off < 64; off <<= 1) {
    s += __shfl_xor(s, off);
    q += __shfl_xor(q, off);
  }
  const float mean = s * (1.f / 512.f);
  const float var = q * (1.f / 512.f) - mean * mean;
  const float rs = rsqrtf(var + 1e-5f);
  float* op = outf + (size_t)row * 512 + lane * 8;
  float o[8];
  #pragma unroll
  for (int i = 0; i < 8; ++i)
    o[i] = (v[i] - mean) * rs * gam[lane * 8 + i] + bet[lane * 8 + i];
  *(float4*)op = make_float4(o[0], o[1], o[2], o[3]);
  *(float4*)(op + 4) = make_float4(o[4], o[5], o[6], o[7]);
}

// ---------------- convert / batched transposes -----------------------------
__global__ __launch_bounds__(256, 4) void conv_k(const float* __restrict__ in, bf16u* __restrict__ out) {
  const size_t i = ((size_t)blockIdx.x * 256 + threadIdx.x) * 8;
  const float4 a = *(const float4*)(in + i);
  const float4 b = *(const float4*)(in + i + 4);
  union { bf16u u[8]; short8 v; } pk;
  pk.u[0] = f2bf(a.x); pk.u[1] = f2bf(a.y); pk.u[2] = f2bf(a.z); pk.u[3] = f2bf(a.w);
  pk.u[4] = f2bf(b.x); pk.u[5] = f2bf(b.y); pk.u[6] = f2bf(b.z); pk.u[7] = f2bf(b.w);
  *(short8*)(out + i) = pk.v;
}

struct P8 { const float* w[8]; };

__global__ __launch_bounds__(256, 4) void trans8_k(
    P8 ps, bf16u* __restrict__ WT0, int K, int N)
{
  const float* W = ps.w[blockIdx.z];
  bf16u* WT = WT0 + (size_t)blockIdx.z * K * N;
  __shared__ float t[32][33];
  const int tx = threadIdx.x & 31, ty = threadIdx.x >> 5;
  const int n0 = blockIdx.x * 32, k0 = blockIdx.y * 32;
  #pragma unroll
  for (int i = 0; i < 4; ++i)
    t[ty + i * 8][tx] = W[(size_t)(k0 + ty + i * 8) * N + n0 + tx];
  __syncthreads();
  #pragma unroll
  for (int i = 0; i < 4; ++i)
    WT[(size_t)(n0 + ty + i * 8) * K + k0 + tx] = f2bf(t[tx][ty + i * 8]);
}

__global__ __launch_bounds__(256, 4) void trans_s_k(
    const float* __restrict__ W0, size_t wstride,
    bf16u* __restrict__ WT0, size_t tstride, int K, int N)
{
  const float* W = W0 + (size_t)blockIdx.z * wstride;
  bf16u* WT = WT0 + (size_t)blockIdx.z * tstride;
  __shared__ float t[32][33];
  const int tx = threadIdx.x & 31, ty = threadIdx.x >> 5;
  const int n0 = blockIdx.x * 32, k0 = blockIdx.y * 32;
  #pragma unroll
  for (int i = 0; i < 4; ++i)
    t[ty + i * 8][tx] = W[(size_t)(k0 + ty + i * 8) * N + n0 + tx];
  __syncthreads();
  #pragma unroll
  for (int i = 0; i < 4; ++i)
    WT[(size_t)(n0 + ty + i * 8) * K + k0 + tx] = f2bf(t[tx][ty + i * 8]);
}

// ---------------- host orchestration -------------------------------------
extern "C" void kernel_launch(void* const* d_in, const int* in_sizes, int n_in,
                              void* d_out, int out_size, void* d_ws, size_t ws_size,
                              hipStream_t stream)
{
  const int B = 16, S = 1024, T = 512, D = 512, DF = 2048, E = 4;
  const int M = B * S;      // 16384
  const int Mc = B * T;     // 8192
  (void)in_sizes; (void)n_in; (void)out_size;

  const float* x      = (const float*)d_in[0];
  const float* cross  = (const float*)d_in[1];
  const float* gate_w = (const float*)d_in[18];
  const float* gate_b = (const float*)d_in[19];
  const float* exp_w1 = (const float*)d_in[20];
  const float* exp_b1 = (const float*)d_in[21];
  const float* exp_w2 = (const float*)d_in[22];
  const float* exp_b2 = (const float*)d_in[23];

  char* p = (char*)d_ws;
  auto alloc = [&](size_t bytes) -> char* {
    char* r = p;
    p += (bytes + 255) & ~(size_t)255;
    return r;
  };
  // ---- persistent ----
  bf16u* w1T   = (bf16u*)alloc((size_t)E * DF * D * 2);   // [8192][512]
  bf16u* w2T   = (bf16u*)alloc((size_t)D * E * DF * 2);   // [512][8192]
  float* xf    = (float*)alloc((size_t)M * D * 4);
  bf16u* x2b   = (bf16u*)alloc((size_t)M * D * 2);
  float* gates = (float*)alloc((size_t)M * 4 * 4);
  float* imp   = (float*)alloc(256);
  float* y     = (float*)alloc((size_t)M * D * 4);
  float* qkvb  = (float*)alloc(1536 * 4);
  float* kvb   = (float*)alloc(1024 * 4);

  // ---- union region: attn-phase scratch OR MoE hbuf ----
  char* upool = p;
  bf16u* xb  = (bf16u*)upool;
  bf16u* crb = xb  + (size_t)M * D;
  bf16u* wT  = crb + (size_t)Mc * D;
  bf16u* qb  = wT  + (size_t)8 * D * D;
  bf16u* kb  = qb  + (size_t)M * D;
  bf16u* vTb = kb  + (size_t)M * D;
  bf16u* ao  = vTb + (size_t)M * D;
  const size_t attnPool = ((size_t)M * D * 5 + (size_t)Mc * D + (size_t)8 * D * D) * 2;
  bf16u* hbuf = (bf16u*)upool;
  const size_t persistent = (size_t)(upool - (char*)d_ws);
  const size_t perE = (size_t)M * DF * 2;   // 67.1 MB
  const size_t rem = ws_size > persistent ? ws_size - persistent : 0;
  const int EC = (rem >= 4 * perE && rem >= attnPool) ? 4
               : (rem >= 2 * perE && rem >= attnPool) ? 2 : 1;

  hipMemsetAsync(imp, 0, 32, stream);
  hipMemcpyAsync(qkvb,        d_in[3], 512 * 4, hipMemcpyDeviceToDevice, stream);
  hipMemcpyAsync(qkvb + 512,  d_in[5], 512 * 4, hipMemcpyDeviceToDevice, stream);
  hipMemcpyAsync(qkvb + 1024, d_in[7], 512 * 4, hipMemcpyDeviceToDevice, stream);
  hipMemcpyAsync(kvb,         d_in[13], 512 * 4, hipMemcpyDeviceToDevice, stream);
  hipMemcpyAsync(kvb + 512,   d_in[15], 512 * 4, hipMemcpyDeviceToDevice, stream);

  conv_k<<<(M * D) / 2048, 256, 0, stream>>>(x, xb);
  conv_k<<<(Mc * D) / 2048, 256, 0, stream>>>(cross, crb);
  {
    P8 ps;
    for (int i = 0; i < 8; ++i) ps.w[i] = (const float*)d_in[2 + 2 * i];
    trans8_k<<<dim3(D / 32, D / 32, 8), 256, 0, stream>>>(ps, wT, D, D);
  }
  trans_s_k<<<dim3(DF / 32, D / 32, 4), 256, 0, stream>>>(
      exp_w1, (size_t)D * DF, w1T, (size_t)DF * D, D, DF);
  trans_s_k<<<dim3(D / 32, (E * DF) / 32, 1), 256, 0, stream>>>(
      exp_w2, 0, w2T, 0, E * DF, D);

  const int gATT = B * 8 * (S / 64);   // 2048

  // ---- self-attention ----
  gemm_k<EPI_QKV><<<(M / 128) * 12, 256, 0, stream>>>(
      xb, 512, wT, 512, qkvb, nullptr, nullptr, qb, kb, vTb, nullptr, 1536, 512, 10, 0, 0);
  attn_k<true><<<gATT, 256, 0, stream>>>(qb, kb, vTb, ao, S, S);
  gemm_k<EPI_RES><<<(M / 128) * 4, 256, 0, stream>>>(
      ao, 512, wT + 3 * (size_t)D * D, 512, (const float*)d_in[9], x, nullptr,
      nullptr, nullptr, nullptr, xf, 512, 512, 0, 0, 0);
  ln_k<false, true, false><<<M / 4, 256, 0, stream>>>(
      xf, nullptr, (const float*)d_in[24], (const float*)d_in[25], xf, x2b,
      nullptr, nullptr, nullptr, nullptr);

  // ---- cross-attention ----
  gemm_k<EPI_BF16><<<(M / 128) * 4, 256, 0, stream>>>(
      x2b, 512, wT + 4 * (size_t)D * D, 512, (const float*)d_in[11], nullptr, nullptr,
      qb, nullptr, nullptr, nullptr, 512, 512, 0, 0, 0);
  gemm_k<EPI_KV><<<(Mc / 128) * 8, 256, 0, stream>>>(
      crb, 512, wT + 5 * (size_t)D * D, 512, kvb, nullptr, nullptr,
      nullptr, kb, vTb, nullptr, 1024, 512, 9, 0, 0);
  attn_k<false><<<gATT, 256, 0, stream>>>(qb, kb, vTb, ao, S, T);
  gemm_k<EPI_RES><<<(M / 128) * 4, 256, 0, stream>>>(
      ao, 512, wT + 7 * (size_t)D * D, 512, (const float*)d_in[17], xf, nullptr,
      nullptr, nullptr, nullptr, xf, 512, 512, 0, 0, 0);
  // ln2 with fused gating (+imp accumulation)
  ln_k<false, true, true><<<M / 4, 256, 0, stream>>>(
      xf, nullptr, (const float*)d_in[26], (const float*)d_in[27], xf, x2b,
      gate_w, gate_b, gates, imp);

  // ---- MoE ----
  const int NC = E / EC;
  const int Nh = EC * DF;
  for (int c = 0; c < NC; ++c) {
    gemm_k<EPI_RELU_GATE><<<(M / 128) * (Nh / 128), 256, 0, stream>>>(
        x2b, 512, w1T + (size_t)c * Nh * D, 512, exp_b1 + (size_t)c * Nh, nullptr, gates,
        hbuf, nullptr, nullptr, nullptr, Nh, 512, 0, c * EC, 0);
    gemm_k<EPI_F32ACC><<<(M / 128) * 4, 256, 0, stream>>>(
        hbuf, Nh, w2T + (size_t)c * Nh, E * DF, nullptr, nullptr, nullptr,
        nullptr, nullptr, nullptr, y, 512, Nh, 0, 0, c == 0 ? 1 : 0);
  }
  ln_final_k<<<M / 4, 256, 0, stream>>>(
      xf, y, gates, exp_b2, (const float*)d_in[28], (const float*)d_in[29],
      (float*)d_out, imp, (float*)d_out + (size_t)M * D);
}